// Round 7
// baseline (587.615 us; speedup 1.0000x reference)
//
#include <hip/hip_runtime.h>
#include <math.h>

// ---------------------------------------------------------------------------
// GraphConv (2-layer GAT) pipeline.
// GEMMs: split-bf16 MFMA (fp32 = hi+lo bf16 RNE pair along K, K'=2K).
// R7: counted-vmcnt K-loop (T3/T4). R6's __syncthreads drained vmcnt(0) every
//   step -> HBM duty cycle ~40% (1.2TB/s, all pipes idle). Now raw s_barrier
//   + s_waitcnt vmcnt(2)/vmcnt(6): prefetched loads stay in flight across the
//   barrier. Branchless/clamped loads keep per-wave vmem instruction counts
//   uniform (vmcnt semantics count instructions per wave).
// ---------------------------------------------------------------------------

typedef __attribute__((ext_vector_type(8))) short bf16x8;
typedef __attribute__((ext_vector_type(4))) float f32x4;

#define WAIT_VMCNT(N) do { \
    asm volatile("s_waitcnt vmcnt(" #N ")" ::: "memory"); \
    __builtin_amdgcn_sched_barrier(0); } while (0)
#define WAIT_LGKM0() do { \
    asm volatile("s_waitcnt lgkmcnt(0)" ::: "memory"); \
    __builtin_amdgcn_sched_barrier(0); } while (0)
#define BARRIER() do { \
    __builtin_amdgcn_s_barrier(); \
    asm volatile("" ::: "memory"); \
    __builtin_amdgcn_sched_barrier(0); } while (0)

__device__ __forceinline__ float gelu_exact(float x) {
    return 0.5f * x * (1.0f + erff(x * 0.70710678118654752f));
}

// round-to-nearest-even bf16; returns the f32 bit pattern of the rounded value
__device__ __forceinline__ unsigned int rne_bf16_bits(float f) {
    unsigned int u = __float_as_uint(f);
    unsigned int r = u + 0x7FFFu + ((u >> 16) & 1u);
    return r & 0xFFFF0000u;
}

// fp32 -> packed (hi bf16 | lo bf16<<16), RNE split.
__device__ __forceinline__ unsigned int packsplit(float f) {
    unsigned int hi_bits = rne_bf16_bits(f);
    float resid = f - __uint_as_float(hi_bits);
    unsigned int lo_bits = rne_bf16_bits(resid);
    return (hi_bits >> 16) | lo_bits;
}

// ---------------------------------------------------------------------------
// conv_wt: W[K][Bcols] fp32 -> Bt tiles, pre-swizzled LDS image (16KB/K-step).
// tile[col*64 + ((kg*8) ^ ((col&7)<<3)) + j]; gemm copies linearly w/ gload_lds.
// ---------------------------------------------------------------------------
__global__ void conv_wt(const float* __restrict__ W, ushort* __restrict__ Bt,
                        int K, int Bcols)
{
    int t = blockIdx.x * 256 + threadIdx.x;
    int KS = K >> 5;
    int total = (Bcols >> 7) * KS * 1024;
    if (t >= total) return;
    int kg    = t & 7;
    int col   = (t >> 3) & 127;
    int rest  = t >> 10;
    int kstep = rest % KS;
    int ct    = rest / KS;
    int gcol  = ct * 128 + col;
    int kbase = kstep * 32 + kg * 4;
    uint4 v;
    v.x = packsplit(W[(size_t)(kbase + 0) * Bcols + gcol]);
    v.y = packsplit(W[(size_t)(kbase + 1) * Bcols + gcol]);
    v.z = packsplit(W[(size_t)(kbase + 2) * Bcols + gcol]);
    v.w = packsplit(W[(size_t)(kbase + 3) * Bcols + gcol]);
    size_t tile = (size_t)(ct * KS + kstep) * 8192;
    *(uint4*)&Bt[tile + col * 64 + ((kg * 8) ^ ((col & 7) << 3))] = v;
}

// ---------------------------------------------------------------------------
// Split-bf16 MFMA GEMM, tile 64x128, 4 waves, dbuf LDS, counted-vmcnt loop.
// MODE=0 (layer): blockIdx.y = col-tile; MODE=1 (upscale): y selects matrix,
//   epilogue gelu(acc+bias) scattered to C[ci[row]*256 + cb + col].
// ---------------------------------------------------------------------------
template<int MODE>
__global__ __launch_bounds__(256)
void gemm64(const float* __restrict__ A0, const float* __restrict__ A1,
            const ushort* __restrict__ B0, const ushort* __restrict__ B1,
            const float* __restrict__ bias0, const float* __restrict__ bias1,
            float* __restrict__ C, const int* __restrict__ ci,
            int M, int K, int cb0, int cb1)
{
    __shared__ ushort As[2][64 * 64];     // 8KB per buffer
    __shared__ ushort Bs[2][128 * 64];    // 16KB per buffer

    const int tid  = threadIdx.x;
    const int lane = tid & 63;
    const int w    = tid >> 6;
    const int wr   = w >> 1, wc = w & 1;
    const int row0 = blockIdx.x * 64;
    const int KS   = K >> 5;

    const float* A; const ushort* Btile; const float* bias; int col_base, colt;
    if (MODE == 1) {
        int sel = blockIdx.y;
        A = sel ? A1 : A0; Btile = sel ? B1 : B0;
        bias = sel ? bias1 : bias0; col_base = sel ? cb1 : cb0; colt = 0;
    } else {
        A = A0; Btile = B0 + (size_t)blockIdx.y * KS * 8192;
        bias = nullptr; col_base = 0; colt = blockIdx.y * 128;
    }

    const int ar0 = tid >> 3;
    const int ac4 = (tid & 7) * 4;

    f32x4 acc[2][4];
#pragma unroll
    for (int m = 0; m < 2; m++)
#pragma unroll
        for (int n = 0; n < 4; n++) acc[m][n] = (f32x4)0.f;

    // branchless (always 2 vmem instrs): clamp row & kstep
    auto loadA = [&](float4* rg, int ks) {
        int kk = ks < KS ? ks : KS - 1;
#pragma unroll
        for (int p = 0; p < 2; p++) {
            int gr = row0 + ar0 + p * 32;
            if (gr >= M) gr = M - 1;
            rg[p] = *(const float4*)&A[(size_t)gr * K + kk * 32 + ac4];
        }
    };
    auto writeA = [&](int buf, const float4* rg) {
#pragma unroll
        for (int p = 0; p < 2; p++) {
            int r = ar0 + p * 32;
            uint4 wv;
            wv.x = packsplit(rg[p].x); wv.y = packsplit(rg[p].y);
            wv.z = packsplit(rg[p].z); wv.w = packsplit(rg[p].w);
            *(uint4*)&As[buf][r * 64 + ((2 * ac4) ^ ((r & 7) << 3))] = wv;
        }
    };
    // always 4 gload_lds instrs; clamp kstep (tail restage is harmless)
    auto stageB = [&](int buf, int ks) {
        int kk = ks < KS ? ks : KS - 1;
        const ushort* tp = Btile + (size_t)kk * 8192;
#pragma unroll
        for (int q = 0; q < 4; q++) {
            int off = (w * 4 + q) * 512;
            __builtin_amdgcn_global_load_lds(
                (const __attribute__((address_space(1))) void*)(tp + off + lane * 8),
                (__attribute__((address_space(3))) void*)(&Bs[buf][off]),
                16, 0, 0);
        }
    };
    auto compute = [&](int buf) {
        bf16x8 af[2][2], bfr[4][2];
#pragma unroll
        for (int m = 0; m < 2; m++) {
            int row = wr * 32 + m * 16 + (lane & 15);
#pragma unroll
            for (int kb = 0; kb < 2; kb++) {
                int kp = kb * 32 + (lane >> 4) * 8;
                af[m][kb] = *(const bf16x8*)&As[buf][row * 64 + (kp ^ ((row & 7) << 3))];
            }
        }
#pragma unroll
        for (int n = 0; n < 4; n++) {
            int cq = wc * 64 + n * 16 + (lane & 15);
#pragma unroll
            for (int kb = 0; kb < 2; kb++) {
                int kp = kb * 32 + (lane >> 4) * 8;
                bfr[n][kb] = *(const bf16x8*)&Bs[buf][cq * 64 + (kp ^ ((cq & 7) << 3))];
            }
        }
#pragma unroll
        for (int m = 0; m < 2; m++)
#pragma unroll
            for (int n = 0; n < 4; n++) {
                acc[m][n] = __builtin_amdgcn_mfma_f32_16x16x32_bf16(
                    af[m][0], bfr[n][0], acc[m][n], 0, 0, 0);
                acc[m][n] = __builtin_amdgcn_mfma_f32_16x16x32_bf16(
                    af[m][1], bfr[n][1], acc[m][n], 0, 0, 0);
            }
    };

    // ---- prologue ----
    // issue order (oldest->newest): A(0)x2, B(0)x4  -> wait A(0): vmcnt(4)
    float4 a0[2], aprev[2];
    loadA(a0, 0);
    stageB(0, 0);
    WAIT_VMCNT(4);
    writeA(0, a0);
    loadA(aprev, 1);          // outstanding now: B(0)x4, A(1)x2
    WAIT_LGKM0();             // own As[0] writes done (barrier at loop top)

    int cur = 0;
    for (int ks = 0; ks < KS; ++ks) {
        int nxt = cur ^ 1;
        // top sync: own B(cur) complete (leave A(ks+1) in flight), then barrier
        WAIT_VMCNT(2);
        BARRIER();
        compute(cur);                 // ds_read As/Bs[cur] + 16 MFMA
        stageB(nxt, ks + 1);          // 4 gload_lds  (clamped at tail)
        float4 anew[2];
        loadA(anew, ks + 2);          // 2 loads      (clamped at tail)
        // outstanding: A(ks+1)x2 (oldest), B(ks+1)x4, A(ks+2)x2 -> wait A(ks+1)
        WAIT_VMCNT(6);
        writeA(nxt, aprev);
        WAIT_LGKM0();                 // own ds_writes done before next barrier
        aprev[0] = anew[0]; aprev[1] = anew[1];
        cur = nxt;
    }

    // ---- epilogue: C/D layout col=lane&15, row=(lane>>4)*4+reg ----
#pragma unroll
    for (int m = 0; m < 2; m++) {
        int rbase = row0 + wr * 32 + m * 16 + ((lane >> 4) << 2);
#pragma unroll
        for (int n = 0; n < 4; n++) {
            int col = wc * 64 + n * 16 + (lane & 15);
#pragma unroll
            for (int j = 0; j < 4; j++) {
                int grow = rbase + j;
                if (grow >= M) continue;
                float v = acc[m][n][j];
                if (MODE == 1) {
                    v = gelu_exact(v + bias[col]);
                    C[(size_t)ci[grow] * 256 + col_base + col] = v;
                } else {
                    C[(size_t)grow * 256 + colt + col] = v;
                }
            }
        }
    }
}

// per-node attention scores
__global__ __launch_bounds__(256)
void scores_kernel(const float* __restrict__ h, const float* __restrict__ asrc,
                   const float* __restrict__ adst, float* __restrict__ s_src,
                   float* __restrict__ s_dst, int N)
{
    int wave = threadIdx.x >> 6;
    int lane = threadIdx.x & 63;
    int n = blockIdx.x * 4 + wave;
    if (n >= N) return;
    float4 hv = *(const float4*)&h[(size_t)n * 256 + lane * 4];
    float4 av = *(const float4*)&asrc[lane * 4];
    float4 dv = *(const float4*)&adst[lane * 4];
    float ps = hv.x * av.x + hv.y * av.y + hv.z * av.z + hv.w * av.w;
    float pd = hv.x * dv.x + hv.y * dv.y + hv.z * dv.z + hv.w * dv.w;
#pragma unroll
    for (int off = 32; off; off >>= 1) {
        ps += __shfl_xor(ps, off);
        pd += __shfl_xor(pd, off);
    }
    if (lane == 0) { s_src[n] = ps; s_dst[n] = pd; }
}

// ---- CSR build ----
__global__ void init_cnt(int* cnt, int N) {
    int i = blockIdx.x * 256 + threadIdx.x;
    if (i < N) cnt[i] = 1;
}

__global__ void count_edges(const int* __restrict__ edges, int* cnt, int E) {
    int e = blockIdx.x * 256 + threadIdx.x;
    if (e < E) atomicAdd(&cnt[edges[2 * e + 1]], 1);
}

__global__ void scan1(const int* __restrict__ cnt, int* __restrict__ rs,
                      int* __restrict__ bsum, int N)
{
    __shared__ int sm[256];
    int tid = threadIdx.x;
    int i = blockIdx.x * 256 + tid;
    int v = (i < N) ? cnt[i] : 0;
    sm[tid] = v;
    __syncthreads();
    for (int off = 1; off < 256; off <<= 1) {
        int t = (tid >= off) ? sm[tid - off] : 0;
        __syncthreads();
        sm[tid] += t;
        __syncthreads();
    }
    if (i < N) rs[i] = sm[tid] - v;
    if (tid == 255) bsum[blockIdx.x] = sm[255];
}

__global__ void scan2(int* bsum, int nb) {
    __shared__ int sm[256];
    int tid = threadIdx.x;
    int v = (tid < nb) ? bsum[tid] : 0;
    sm[tid] = v;
    __syncthreads();
    for (int off = 1; off < 256; off <<= 1) {
        int t = (tid >= off) ? sm[tid - off] : 0;
        __syncthreads();
        sm[tid] += t;
        __syncthreads();
    }
    if (tid < nb) bsum[tid] = sm[tid] - v;
}

__global__ void scan3(int* __restrict__ rs, const int* __restrict__ bsum,
                      int N, int total)
{
    int i = blockIdx.x * 256 + threadIdx.x;
    if (i < N) rs[i] += bsum[i >> 8];
    if (i == 0) rs[N] = total;
}

__global__ void copy_cursor(const int* __restrict__ rs, int* __restrict__ cur, int N) {
    int i = blockIdx.x * 256 + threadIdx.x;
    if (i < N) cur[i] = rs[i];
}

__global__ void fill_csr(const int* __restrict__ edges, int* __restrict__ cur,
                         int* __restrict__ col, int E, int N)
{
    int i = blockIdx.x * 256 + threadIdx.x;
    if (i < E) {
        int s = edges[2 * i], d = edges[2 * i + 1];
        col[atomicAdd(&cur[d], 1)] = s;
    } else if (i < E + N) {
        int n = i - E;
        col[atomicAdd(&cur[n], 1)] = n;
    }
}

// ---------------------------------------------------------------------------
// attn: block per dst node, 2-phase; phase 2 keeps 4 h-rows in flight per wave.
// ---------------------------------------------------------------------------
template<int EPI>
__global__ __launch_bounds__(256)
void attn_kernel(const float* __restrict__ h, const float* __restrict__ s_src,
                 const float* __restrict__ s_dst, const int* __restrict__ rs,
                 const int* __restrict__ colv, const float* __restrict__ bias,
                 float* __restrict__ out, int N)
{
    __shared__ float wlds[256];
    __shared__ int   slds[256];
    __shared__ float red[4][256];
    __shared__ float dred[4];

    const int n    = blockIdx.x;
    const int tid  = threadIdx.x;
    const int w    = tid >> 6;
    const int lane = tid & 63;

    const float sd = s_dst[n];
    const int beg = rs[n], end = rs[n + 1];

    float4 acc = make_float4(0.f, 0.f, 0.f, 0.f);
    float den = 0.f;

    for (int c0 = beg; c0 < end; c0 += 256) {
        const int cnt = min(256, end - c0);
        __syncthreads();
        if (tid < cnt) {
            int src = colv[c0 + tid];
            float e = s_src[src] + sd;
            e = (e > 0.f) ? e : 0.2f * e;
            wlds[tid] = __expf(e);
            slds[tid] = src;
        }
        __syncthreads();

        int i = w;
        for (; i + 12 < cnt; i += 16) {
            int   s0 = slds[i],      s1 = slds[i + 4];
            int   s2 = slds[i + 8],  s3 = slds[i + 12];
            float w0 = wlds[i],      w1 = wlds[i + 4];
            float w2 = wlds[i + 8],  w3 = wlds[i + 12];
            float4 h0 = *(const float4*)&h[(size_t)s0 * 256 + lane * 4];
            float4 h1 = *(const float4*)&h[(size_t)s1 * 256 + lane * 4];
            float4 h2 = *(const float4*)&h[(size_t)s2 * 256 + lane * 4];
            float4 h3 = *(const float4*)&h[(size_t)s3 * 256 + lane * 4];
            acc.x = fmaf(w0, h0.x, acc.x); acc.y = fmaf(w0, h0.y, acc.y);
            acc.z = fmaf(w0, h0.z, acc.z); acc.w = fmaf(w0, h0.w, acc.w);
            acc.x = fmaf(w1, h1.x, acc.x); acc.y = fmaf(w1, h1.y, acc.y);
            acc.z = fmaf(w1, h1.z, acc.z); acc.w = fmaf(w1, h1.w, acc.w);
            acc.x = fmaf(w2, h2.x, acc.x); acc.y = fmaf(w2, h2.y, acc.y);
            acc.z = fmaf(w2, h2.z, acc.z); acc.w = fmaf(w2, h2.w, acc.w);
            acc.x = fmaf(w3, h3.x, acc.x); acc.y = fmaf(w3, h3.y, acc.y);
            acc.z = fmaf(w3, h3.z, acc.z); acc.w = fmaf(w3, h3.w, acc.w);
            den += w0 + w1 + w2 + w3;
        }
        for (; i < cnt; i += 4) {
            int   s0 = slds[i];
            float w0 = wlds[i];
            float4 h0 = *(const float4*)&h[(size_t)s0 * 256 + lane * 4];
            acc.x = fmaf(w0, h0.x, acc.x); acc.y = fmaf(w0, h0.y, acc.y);
            acc.z = fmaf(w0, h0.z, acc.z); acc.w = fmaf(w0, h0.w, acc.w);
            den += w0;
        }
    }

    *(float4*)&red[w][lane * 4] = acc;
    if (lane == 0) dred[w] = den;
    __syncthreads();

    float v  = red[0][tid] + red[1][tid] + red[2][tid] + red[3][tid];
    float dn = dred[0] + dred[1] + dred[2] + dred[3];
    v = v / dn + bias[tid];
    out[(size_t)n * 256 + tid] = (EPI == 1) ? gelu_exact(v) : fmaxf(v, 0.f);
}

extern "C" void kernel_launch(void* const* d_in, const int* in_sizes, int n_in,
                              void* d_out, int out_size, void* d_ws, size_t ws_size,
                              hipStream_t stream)
{
    const float* img    = (const float*)d_in[0];
    const float* txt    = (const float*)d_in[1];
    const int*   ci     = (const int*)d_in[2];
    const int*   edges  = (const int*)d_in[3];
    const float* w_img  = (const float*)d_in[4];
    const float* b_img  = (const float*)d_in[5];
    const float* w_text = (const float*)d_in[6];
    const float* b_text = (const float*)d_in[7];
    const float* W0     = (const float*)d_in[8];
    const float* asrc0  = (const float*)d_in[9];
    const float* adst0  = (const float*)d_in[10];
    const float* bias0  = (const float*)d_in[11];
    const float* W1     = (const float*)d_in[12];
    const float* asrc1  = (const float*)d_in[13];
    const float* adst1  = (const float*)d_in[14];
    const float* bias1  = (const float*)d_in[15];

    const int N = in_sizes[2];
    const int E = in_sizes[3] / 2;
    const int T = E + N;

    float* fA   = (float*)d_ws;                    // node, later h1   N*256
    float* fB   = fA + (size_t)N * 256;            // out0             N*256
    float* sS   = fB + (size_t)N * 256;            // N
    float* sD   = sS + N;                          // N
    int*   rs   = (int*)(sD + N);                  // N+1
    int*   cur  = rs + (N + 1);                    // N
    int*   col  = cur + N;                         // E+N
    int*   bsum = col + T;                         // <=256
    uintptr_t bt0 = ((uintptr_t)(bsum + 256) + 63) & ~(uintptr_t)63;
    ushort* BtImg = (ushort*)bt0;                  // 24 tiles x 8192
    ushort* BtTxt = BtImg + 24 * 8192;             // 24 tiles x 8192
    ushort* BtW0  = BtTxt + 24 * 8192;             // 16 tiles x 8192
    ushort* BtW1  = BtW0  + 16 * 8192;             // 16 tiles x 8192
    float* h0   = (float*)d_out;                   // N*256 scratch

    const int nb256 = (N + 255) / 256;
    const int nbT   = (T + 255) / 256;
    const int gm64  = (N + 63) / 64;               // 782

    conv_wt<<<(1 * 24 * 1024 + 255) / 256, 256, 0, stream>>>(w_img,  BtImg, 768, 128);
    conv_wt<<<(1 * 24 * 1024 + 255) / 256, 256, 0, stream>>>(w_text, BtTxt, 768, 128);
    conv_wt<<<(2 * 8  * 1024 + 255) / 256, 256, 0, stream>>>(W0,     BtW0,  256, 256);
    conv_wt<<<(2 * 8  * 1024 + 255) / 256, 256, 0, stream>>>(W1,     BtW1,  256, 256);

    // merged upscale GEMMs: grid (782, 2), y selects img/text set
    gemm64<1><<<dim3(gm64, 2), 256, 0, stream>>>(
        img, txt, BtImg, BtTxt, b_img, b_text, fA, ci, N, 768, 0, 128);

    init_cnt<<<nb256, 256, 0, stream>>>(cur, N);
    count_edges<<<(E + 255) / 256, 256, 0, stream>>>(edges, cur, E);
    scan1<<<nb256, 256, 0, stream>>>(cur, rs, bsum, N);
    scan2<<<1, 256, 0, stream>>>(bsum, nb256);
    scan3<<<nb256, 256, 0, stream>>>(rs, bsum, N, T);
    copy_cursor<<<nb256, 256, 0, stream>>>(rs, cur, N);
    fill_csr<<<nbT, 256, 0, stream>>>(edges, cur, col, E, N);

    // ---- layer 0 ----
    gemm64<0><<<dim3(gm64, 2), 256, 0, stream>>>(
        fA, nullptr, BtW0, nullptr, nullptr, nullptr, h0, nullptr, N, 256, 0, 0);
    scores_kernel<<<(N + 3) / 4, 256, 0, stream>>>(h0, asrc0, adst0, sS, sD, N);
    attn_kernel<0><<<N, 256, 0, stream>>>(h0, sS, sD, rs, col, bias0, fB, N);

    // ---- layer 1 ----
    gemm64<0><<<dim3(gm64, 2), 256, 0, stream>>>(
        fB, nullptr, BtW1, nullptr, nullptr, nullptr, fA, nullptr, N, 256, 0, 0);
    scores_kernel<<<(N + 3) / 4, 256, 0, stream>>>(fA, asrc1, adst1, sS, sD, N);
    attn_kernel<1><<<N, 256, 0, stream>>>(fA, sS, sD, rs, col, bias1, (float*)d_out, N);
}